// Round 8
// baseline (299.878 us; speedup 1.0000x reference)
//
#include <hip/hip_runtime.h>
#include <math.h>

#define DIM   512
#define NB    4
#define NS    8192
#define FFT_N 8192
#define FT    1024
#define MTOT  (NB*NS)

// padded LDS index map: +1 float2 per 8 -> kills power-of-2 bank aliasing
#define IDX(i) ((i) + ((i) >> 3))
#define XSZ   9216

typedef __attribute__((ext_vector_type(8))) short bf16x8;
typedef __attribute__((ext_vector_type(4))) short short4v;
typedef __attribute__((ext_vector_type(8))) short short8v;
typedef __attribute__((ext_vector_type(4))) float f32x4;

// ---------------------------------------------------------------- helpers
__device__ __forceinline__ float bf2f(unsigned short u) {
    union { unsigned int i; float f; } v; v.i = ((unsigned int)u) << 16; return v.f;
}
__device__ __forceinline__ unsigned short f2bf(float f) {
    union { float f; unsigned int i; } v; v.f = f;
    unsigned int r = v.i + 0x7fffu + ((v.i >> 16) & 1u);
    return (unsigned short)(r >> 16);
}
__device__ __forceinline__ float2 cmulf(float2 a, float2 b) {
    return make_float2(a.x*b.x - a.y*b.y, a.x*b.y + a.y*b.x);
}
__device__ __forceinline__ float2 cadd(float2 a, float2 b) { return make_float2(a.x+b.x, a.y+b.y); }
__device__ __forceinline__ float2 csub(float2 a, float2 b) { return make_float2(a.x-b.x, a.y-b.y); }
__device__ __forceinline__ float gelu_exact(float x) {
    return 0.5f * x * (1.0f + erff(x * 0.70710678118654752f));
}
__device__ __forceinline__ void gload16(const void* g, void* l) {
    __builtin_amdgcn_global_load_lds((const __attribute__((address_space(1))) void*)g,
                                     (__attribute__((address_space(3))) void*)l, 16, 0, 0);
}

// ---------------------------------------------------------------- filter MLP
__global__ void filter_mlp_kernel(const float* __restrict__ w1, const float* __restrict__ b1,
                                  const float* __restrict__ w2, const float* __restrict__ b2,
                                  const float* __restrict__ w3, const float* __restrict__ b3,
                                  float* __restrict__ filt) {
    __shared__ float h1[64];
    __shared__ float h2[64];
    const int s = blockIdx.x;
    const int t = threadIdx.x;          // 64 threads
    const float pos = (float)s / (float)(NS - 1);
    h1[t] = gelu_exact(pos * w1[t] + b1[t]);
    __syncthreads();
    float acc = b2[t];
    #pragma unroll 8
    for (int j = 0; j < 64; ++j) acc += h1[j] * w2[j*64 + t];
    h2[t] = gelu_exact(acc);
    __syncthreads();
    for (int d = t; d < DIM; d += 64) {
        float o = b3[d];
        #pragma unroll 8
        for (int j = 0; j < 64; ++j) o += h2[j] * w3[j*DIM + d];
        filt[(size_t)s*DIM + d] = o;
    }
}

// ------------------------------------------------- fp32 transpose (R,C)->(C,R)
__global__ void transpose_f32_kernel(const float* __restrict__ in, float* __restrict__ out,
                                     int R, int C) {
    __shared__ float tile[64][65];
    const int c0 = blockIdx.x * 64, r0 = blockIdx.y * 64;
    const int t = threadIdx.x;
    const int rr = t >> 4, c4 = (t & 15) * 4;
    #pragma unroll
    for (int p = 0; p < 4; ++p) {
        const int r = rr + p*16;
        float4 v = *(const float4*)&in[(size_t)(r0 + r)*C + c0 + c4];
        tile[r][c4+0]=v.x; tile[r][c4+1]=v.y; tile[r][c4+2]=v.z; tile[r][c4+3]=v.w;
    }
    __syncthreads();
    const int cc = t >> 4, r4 = (t & 15) * 4;
    #pragma unroll
    for (int p = 0; p < 4; ++p) {
        const int c = cc + p*16;
        float4 o = make_float4(tile[r4+0][c], tile[r4+1][c], tile[r4+2][c], tile[r4+3][c]);
        *(float4*)&out[(size_t)(c0 + c)*R + r0 + r4] = o;
    }
}

// ------------------------------------------- cast+transpose (R,C)f32->(C,R)bf16
__global__ void castT_kernel(const float* __restrict__ in, unsigned short* __restrict__ outT,
                             int R, int C) {
    __shared__ float tile[64][65];
    const int c0 = blockIdx.x * 64, r0 = blockIdx.y * 64;
    const int t = threadIdx.x;
    const int rr = t >> 4, c4 = (t & 15) * 4;
    #pragma unroll
    for (int p = 0; p < 4; ++p) {
        const int r = rr + p*16;
        float4 v = *(const float4*)&in[(size_t)(r0 + r)*C + c0 + c4];
        tile[r][c4+0]=v.x; tile[r][c4+1]=v.y; tile[r][c4+2]=v.z; tile[r][c4+3]=v.w;
    }
    __syncthreads();
    const int cc = t >> 4, r4 = (t & 15) * 4;
    #pragma unroll
    for (int p = 0; p < 4; ++p) {
        const int c = cc + p*16;
        short4v o;
        o[0] = (short)f2bf(tile[r4+0][c]); o[1] = (short)f2bf(tile[r4+1][c]);
        o[2] = (short)f2bf(tile[r4+2][c]); o[3] = (short)f2bf(tile[r4+3][c]);
        *(short4v*)&outT[(size_t)(c0 + c)*R + r0 + r4] = o;
    }
}

// ---------------------------------------------------------------- cast x->bf16
__global__ void cast_x_kernel(const float* __restrict__ in, unsigned short* __restrict__ out) {
    const size_t i = ((size_t)blockIdx.x * 256 + threadIdx.x) * 8;
    float4 a = *(const float4*)&in[i];
    float4 b = *(const float4*)&in[i+4];
    short8v o;
    o[0]=(short)f2bf(a.x); o[1]=(short)f2bf(a.y); o[2]=(short)f2bf(a.z); o[3]=(short)f2bf(a.w);
    o[4]=(short)f2bf(b.x); o[5]=(short)f2bf(b.y); o[6]=(short)f2bf(b.z); o[7]=(short)f2bf(b.w);
    *(short8v*)&out[i] = o;
}

// ---------------------------------------------------------------- FFT pieces
template<int LOGQ>
__device__ __forceinline__ void dif4_stage(float2* X) {
    const int q = 1 << LOGQ;
    const float step = -6.28318530717958647692f / (float)(4*q);
    #pragma unroll
    for (int it = 0; it < (FFT_N/4)/FT; ++it) {
        const int idx = threadIdx.x + it*FT;
        const int g = idx >> LOGQ, k = idx & (q-1);
        const int base = (g << (LOGQ+2)) + k;
        const int i0 = IDX(base), i1 = IDX(base+q), i2 = IDX(base+2*q), i3 = IDX(base+3*q);
        float2 a=X[i0], b=X[i1], c=X[i2], d=X[i3];
        float2 t0=cadd(a,c), t1=csub(a,c), t2=cadd(b,d), t3=csub(b,d);
        float2 y0=cadd(t0,t2), y2=csub(t0,t2);
        float2 y1=make_float2(t1.x+t3.y, t1.y-t3.x);   // t1 - i*t3
        float2 y3=make_float2(t1.x-t3.y, t1.y+t3.x);   // t1 + i*t3
        float sv, cv; __sincosf(step*(float)k, &sv, &cv);
        float2 w1=make_float2(cv, sv);
        float2 w2=cmulf(w1, w1);
        float2 w3=cmulf(w2, w1);
        X[i0] = y0;
        X[i1] = cmulf(y1, w1);
        X[i2] = cmulf(y2, w2);
        X[i3] = cmulf(y3, w3);
    }
    __syncthreads();
}

template<int LOGQ>
__device__ __forceinline__ void dit4_stage_inv(float2* X) {
    const int q = 1 << LOGQ;
    const float step = 6.28318530717958647692f / (float)(4*q);
    #pragma unroll
    for (int it = 0; it < (FFT_N/4)/FT; ++it) {
        const int idx = threadIdx.x + it*FT;
        const int g = idx >> LOGQ, k = idx & (q-1);
        const int base = (g << (LOGQ+2)) + k;
        const int i0 = IDX(base), i1 = IDX(base+q), i2 = IDX(base+2*q), i3 = IDX(base+3*q);
        float sv, cv; __sincosf(step*(float)k, &sv, &cv);
        float2 w1=make_float2(cv, sv);
        float2 w2=cmulf(w1, w1);
        float2 w3=cmulf(w2, w1);
        float2 u0=X[i0];
        float2 u1=cmulf(X[i1], w1);
        float2 u2=cmulf(X[i2], w2);
        float2 u3=cmulf(X[i3], w3);
        float2 s02=cadd(u0,u2), d02=csub(u0,u2);
        float2 s13=cadd(u1,u3), d13=csub(u1,u3);
        X[i0] = cadd(s02, s13);
        X[i2] = csub(s02, s13);
        X[i1] = make_float2(d02.x - d13.y, d02.y + d13.x);   // d02 + i*d13
        X[i3] = make_float2(d02.x + d13.y, d02.y - d13.x);   // d02 - i*d13
    }
    __syncthreads();
}

__device__ __forceinline__ void reg_fwd(float2* E) {
    const float C = 0.70710678118654752f;
    {
        float2 t0=cadd(E[0],E[4]), t1=csub(E[0],E[4]);
        float2 t2=cadd(E[2],E[6]), t3=csub(E[2],E[6]);
        E[0]=cadd(t0,t2);
        E[4]=csub(t0,t2);
        E[2]=make_float2(t1.x+t3.y, t1.y-t3.x);
        E[6]=make_float2(t1.x-t3.y, t1.y+t3.x);
    }
    {
        float2 t0=cadd(E[1],E[5]), t1=csub(E[1],E[5]);
        float2 t2=cadd(E[3],E[7]), t3=csub(E[3],E[7]);
        float2 y0=cadd(t0,t2), y2=csub(t0,t2);
        float2 y1=make_float2(t1.x+t3.y, t1.y-t3.x);
        float2 y3=make_float2(t1.x-t3.y, t1.y+t3.x);
        E[1]=y0;
        E[3]=make_float2(C*(y1.x+y1.y),  C*(y1.y-y1.x));
        E[5]=make_float2(y2.y, -y2.x);
        E[7]=make_float2(C*(y3.y-y3.x), -C*(y3.x+y3.y));
    }
    #pragma unroll
    for (int j = 0; j < 8; j += 2) {
        float2 a=E[j], b=E[j+1];
        E[j]=cadd(a,b); E[j+1]=csub(a,b);
    }
}
__device__ __forceinline__ void reg_inv(float2* E) {
    const float C = 0.70710678118654752f;
    #pragma unroll
    for (int j = 0; j < 8; j += 2) {
        float2 a=E[j], b=E[j+1];
        E[j]=cadd(a,b); E[j+1]=csub(a,b);
    }
    {
        float2 u0=E[0], u1=E[2], u2=E[4], u3=E[6];
        float2 s02=cadd(u0,u2), d02=csub(u0,u2);
        float2 s13=cadd(u1,u3), d13=csub(u1,u3);
        E[0]=cadd(s02,s13);
        E[4]=csub(s02,s13);
        E[2]=make_float2(d02.x - d13.y, d02.y + d13.x);
        E[6]=make_float2(d02.x + d13.y, d02.y - d13.x);
    }
    {
        float2 z1=E[3], z2=E[5], z3=E[7];
        float2 u0=E[1];
        float2 u1=make_float2(C*(z1.x - z1.y), C*(z1.x + z1.y));
        float2 u2=make_float2(-z2.y, z2.x);
        float2 u3=make_float2(-C*(z3.x + z3.y), C*(z3.x - z3.y));
        float2 s02=cadd(u0,u2), d02=csub(u0,u2);
        float2 s13=cadd(u1,u3), d13=csub(u1,u3);
        E[1]=cadd(s02,s13);
        E[5]=csub(s02,s13);
        E[3]=make_float2(d02.x - d13.y, d02.y + d13.x);
        E[7]=make_float2(d02.x + d13.y, d02.y - d13.x);
    }
}

// thread t owns logical elems 8t..8t+7 == phys 9t..9t+7 (contiguous)
__device__ __forceinline__ void load8p(const float2* X, int t, float2* E) {
    const float2* b = X + 9*t;
    #pragma unroll
    for (int j = 0; j < 8; ++j) E[j] = b[j];
}
__device__ __forceinline__ void store8p(float2* X, int t, const float2* E) {
    float2* b = X + 9*t;
    #pragma unroll
    for (int j = 0; j < 8; ++j) b[j] = E[j];
}

// filter spectrum (permuted order P); filtT (D, S) fp32 rows
__global__ __launch_bounds__(FT)
void fft_filt_kernel(const float* __restrict__ filtT, float2* __restrict__ Fbr) {
    __shared__ float2 X[XSZ];
    const int dd = blockIdx.x;
    const int t = threadIdx.x;
    const float* f = filtT + (size_t)dd * FFT_N;
    {
        float4 a = *(const float4*)(f + 8*t);
        float4 b = *(const float4*)(f + 8*t + 4);
        float2 E[8];
        E[0]=make_float2(a.x,0.f); E[1]=make_float2(a.y,0.f);
        E[2]=make_float2(a.z,0.f); E[3]=make_float2(a.w,0.f);
        E[4]=make_float2(b.x,0.f); E[5]=make_float2(b.y,0.f);
        E[6]=make_float2(b.z,0.f); E[7]=make_float2(b.w,0.f);
        store8p(X, t, E);
    }
    __syncthreads();
    dif4_stage<11>(X);
    dif4_stage<9>(X);
    dif4_stage<7>(X);
    dif4_stage<5>(X);
    dif4_stage<3>(X);
    {
        float2 E[8];
        load8p(X, t, E);
        reg_fwd(E);
        float2* o = Fbr + (size_t)dd*FFT_N + 8*t;
        #pragma unroll
        for (int j = 0; j < 8; ++j) o[j] = E[j];
    }
}

// packed-pair circular conv, in-place bf16: rows (2p,d) and (2p+1,d) of uT
__global__ __launch_bounds__(FT)
void fft_conv_kernel(unsigned short* __restrict__ uT, const float2* __restrict__ Fbr) {
    __shared__ float2 X[XSZ];
    const int d = blockIdx.x & (DIM - 1);
    const int p = blockIdx.x >> 9;
    unsigned short* u1 = uT + (size_t)((2*p    )*DIM + d) * FFT_N;
    unsigned short* u2 = uT + (size_t)((2*p + 1)*DIM + d) * FFT_N;
    const int t = threadIdx.x;
    {
        short8v a = *(const short8v*)(u1 + 8*t);
        short8v b = *(const short8v*)(u2 + 8*t);
        float2 E[8];
        #pragma unroll
        for (int j = 0; j < 8; ++j)
            E[j] = make_float2(bf2f((unsigned short)a[j]), bf2f((unsigned short)b[j]));
        store8p(X, t, E);
    }
    __syncthreads();
    dif4_stage<11>(X);
    dif4_stage<9>(X);
    dif4_stage<7>(X);
    dif4_stage<5>(X);
    dif4_stage<3>(X);
    {
        float2 E[8];
        load8p(X, t, E);
        reg_fwd(E);
        const float2* F = Fbr + (size_t)d*FFT_N + 8*t;
        #pragma unroll
        for (int j = 0; j < 8; ++j) E[j] = cmulf(E[j], F[j]);
        reg_inv(E);
        store8p(X, t, E);
    }
    __syncthreads();
    dit4_stage_inv<3>(X);
    dit4_stage_inv<5>(X);
    dit4_stage_inv<7>(X);
    dit4_stage_inv<9>(X);
    dit4_stage_inv<11>(X);
    {
        float2 E[8];
        load8p(X, t, E);
        const float sc = 1.0f / (float)FFT_N;
        short8v a, b;
        #pragma unroll
        for (int j = 0; j < 8; ++j) {
            a[j] = (short)f2bf(E[j].x * sc);
            b[j] = (short)f2bf(E[j].y * sc);
        }
        *(short8v*)(u1 + 8*t) = a;
        *(short8v*)(u2 + 8*t) = b;
    }
}

// ------------------------------------------------- depthwise conv + transpose
__global__ void conv_transpose_kernel(const unsigned short* __restrict__ u,
                                      const float* __restrict__ conv_w,
                                      const float* __restrict__ conv_b,
                                      unsigned short* __restrict__ uT) {
    __shared__ float tile[66][65];
    const int bid = blockIdx.x;
    const int dt = bid & 7, st = (bid >> 3) & 127, b = bid >> 10;
    const int d0 = dt*64, s0 = st*64;
    const int t = threadIdx.x;
    const int rr = t >> 4, c4 = (t & 15) * 4;
    for (int r = rr; r < 66; r += 16) {
        const int s = s0 + r - 1;
        float v0=0.f, v1=0.f, v2=0.f, v3=0.f;
        if (s >= 0 && s < NS) {
            short4v xv = *(const short4v*)&u[((size_t)(b*NS + s))*DIM + d0 + c4];
            v0=bf2f((unsigned short)xv[0]); v1=bf2f((unsigned short)xv[1]);
            v2=bf2f((unsigned short)xv[2]); v3=bf2f((unsigned short)xv[3]);
        }
        tile[r][c4]=v0; tile[r][c4+1]=v1; tile[r][c4+2]=v2; tile[r][c4+3]=v3;
    }
    __syncthreads();
    const int dl = t >> 4, s4 = (t & 15) * 4;
    #pragma unroll
    for (int p = 0; p < 4; ++p) {
        const int dc = dl + p*16;
        const int d = d0 + dc;
        const float w0 = conv_w[d*3], w1 = conv_w[d*3+1], w2 = conv_w[d*3+2];
        const float cb = conv_b[d];
        short4v o;
        #pragma unroll
        for (int j = 0; j < 4; ++j) {
            const int sx = s4 + j;
            const float val = tile[sx][dc]*w0 + tile[sx+1][dc]*w1 + tile[sx+2][dc]*w2 + cb;
            o[j] = (short)f2bf(val);
        }
        *(short4v*)&uT[((size_t)(b*DIM + d))*FFT_N + s0 + s4] = o;
    }
}

// ---------------------------------------------------------------- gating
// vg (B,S,D) bf16 *= y from yT (B,D,S) bf16 (in-place)
__global__ void gate_kernel(unsigned short* __restrict__ vg, const unsigned short* __restrict__ yT) {
    __shared__ float tile[64][65];
    const int bid = blockIdx.x;
    const int dt = bid & 7, st = (bid >> 3) & 127, b = bid >> 10;
    const int d0 = dt*64, s0 = st*64;
    const int t = threadIdx.x;
    const int dl = t >> 4, s4 = (t & 15) * 4;
    #pragma unroll
    for (int p = 0; p < 4; ++p) {
        const int d = dl + p*16;
        short4v y = *(const short4v*)&yT[((size_t)(b*DIM + d0 + d))*FFT_N + s0 + s4];
        tile[d][s4]  =bf2f((unsigned short)y[0]); tile[d][s4+1]=bf2f((unsigned short)y[1]);
        tile[d][s4+2]=bf2f((unsigned short)y[2]); tile[d][s4+3]=bf2f((unsigned short)y[3]);
    }
    __syncthreads();
    const int sl = t >> 4, d4 = (t & 15) * 4;
    #pragma unroll
    for (int p = 0; p < 4; ++p) {
        const int s = s0 + sl + p*16;
        unsigned short* pv = &vg[((size_t)(b*NS + s))*DIM + d0 + d4];
        short4v v = *(short4v*)pv;
        short4v o;
        #pragma unroll
        for (int j = 0; j < 4; ++j)
            o[j] = (short)f2bf(bf2f((unsigned short)v[j]) * tile[d4+j][sl + p*16]);
        *(short4v*)pv = o;
    }
}

// ---------------------------------------------------------------- bf16 GEMM
// Double-buffered pipeline + XCD swizzle. Grid must be dim3(4, 256).
// MODE 0: Cb = bf16(val);  MODE 2: Cf = val (fp32)
template<int MODE>
__global__ __launch_bounds__(256)
void gemm_bt_kernel(const unsigned short* __restrict__ A,
                    const unsigned short* __restrict__ BT,
                    const float* __restrict__ bias,
                    float* __restrict__ Cf,
                    unsigned short* __restrict__ Cb) {
    __shared__ unsigned short As[2][4096];
    __shared__ unsigned short Bs[2][4096];
    const int tid = threadIdx.x;
    const int wid = tid >> 6, lane = tid & 63;
    const int bid = blockIdx.y * 4 + blockIdx.x;
    const int swz = (bid & 7) * 128 + (bid >> 3);
    const int m0 = (swz >> 2) * 128, n0 = (swz & 3) * 128;
    const int srow = wid*16 + (lane >> 2);
    const int scol = (lane & 3) * 8;
    const unsigned short* gA = A  + (size_t)(m0 + srow)*DIM + scol;
    const unsigned short* gB = BT + (size_t)(n0 + srow)*DIM + scol;
    const int wr = wid >> 1, wc = wid & 1;
    const int fr = lane & 15, fq = lane >> 4;
    f32x4 acc[4][4] = {};
    gload16(gA,                  &As[0][wid*512]);
    gload16(gA + (size_t)64*DIM, &As[0][wid*512 + 2048]);
    gload16(gB,                  &Bs[0][wid*512]);
    gload16(gB + (size_t)64*DIM, &Bs[0][wid*512 + 2048]);
    int cur = 0;
    for (int k0 = 0; k0 < DIM; k0 += 32) {
        __syncthreads();
        if (k0 + 32 < DIM) {
            const int nx = cur ^ 1;
            gload16(gA + k0 + 32,                  &As[nx][wid*512]);
            gload16(gA + k0 + 32 + (size_t)64*DIM, &As[nx][wid*512 + 2048]);
            gload16(gB + k0 + 32,                  &Bs[nx][wid*512]);
            gload16(gB + k0 + 32 + (size_t)64*DIM, &Bs[nx][wid*512 + 2048]);
        }
        bf16x8 af[4], bfr[4];
        #pragma unroll
        for (int mi = 0; mi < 4; ++mi)
            af[mi] = *(const bf16x8*)&As[cur][(wr*64 + mi*16 + fr)*32 + fq*8];
        #pragma unroll
        for (int ni = 0; ni < 4; ++ni)
            bfr[ni] = *(const bf16x8*)&Bs[cur][(wc*64 + ni*16 + fr)*32 + fq*8];
        #pragma unroll
        for (int mi = 0; mi < 4; ++mi)
            #pragma unroll
            for (int ni = 0; ni < 4; ++ni)
                acc[mi][ni] = __builtin_amdgcn_mfma_f32_16x16x32_bf16(af[mi], bfr[ni], acc[mi][ni], 0, 0, 0);
        cur ^= 1;
    }
    #pragma unroll
    for (int ni = 0; ni < 4; ++ni) {
        const int c = n0 + wc*64 + ni*16 + fr;
        const float bv = bias[c];
        #pragma unroll
        for (int mi = 0; mi < 4; ++mi) {
            const int rbase = m0 + wr*64 + mi*16 + fq*4;
            #pragma unroll
            for (int j = 0; j < 4; ++j) {
                const size_t idx = (size_t)(rbase + j)*DIM + c;
                const float val = acc[mi][ni][j] + bv;
                if (MODE == 0) Cb[idx] = f2bf(val);
                else           Cf[idx] = val;
            }
        }
    }
}

// ---------------- triple GEMM: u = x@Wu+bu ; g0 = (x@Wv+bv)*sigmoid(x@Wz+bz)
__global__ __launch_bounds__(256)
void gemm_vzu_kernel(const unsigned short* __restrict__ A,
                     const unsigned short* __restrict__ BT,   // w_inT (1536,512)
                     const float* __restrict__ bias,          // b_in (1536)
                     unsigned short* __restrict__ Gb,         // g0 (B,S,D)
                     unsigned short* __restrict__ Ub) {       // u  (B,S,D)
    __shared__ unsigned short As[2][4096];
    __shared__ unsigned short Bv[2][4096];
    __shared__ unsigned short Bu[2][4096];
    __shared__ unsigned short Bz[2][4096];
    const int tid = threadIdx.x;
    const int wid = tid >> 6, lane = tid & 63;
    const int bid = blockIdx.y * 4 + blockIdx.x;
    const int swz = (bid & 7) * 128 + (bid >> 3);
    const int m0 = (swz >> 2) * 128, n0 = (swz & 3) * 128;
    const int srow = wid*16 + (lane >> 2);
    const int scol = (lane & 3) * 8;
    const unsigned short* gA  = A  + (size_t)(m0 + srow)*DIM + scol;
    const unsigned short* gBv = BT + (size_t)(n0 + srow)*DIM + scol;
    const unsigned short* gBu = BT + (size_t)(512  + n0 + srow)*DIM + scol;
    const unsigned short* gBz = BT + (size_t)(1024 + n0 + srow)*DIM + scol;
    const int wr = wid >> 1, wc = wid & 1;
    const int fr = lane & 15, fq = lane >> 4;
    f32x4 accv[4][4] = {};
    f32x4 accu[4][4] = {};
    f32x4 accz[4][4] = {};
    gload16(gA,                   &As[0][wid*512]);
    gload16(gA  + (size_t)64*DIM, &As[0][wid*512 + 2048]);
    gload16(gBv,                  &Bv[0][wid*512]);
    gload16(gBv + (size_t)64*DIM, &Bv[0][wid*512 + 2048]);
    gload16(gBu,                  &Bu[0][wid*512]);
    gload16(gBu + (size_t)64*DIM, &Bu[0][wid*512 + 2048]);
    gload16(gBz,                  &Bz[0][wid*512]);
    gload16(gBz + (size_t)64*DIM, &Bz[0][wid*512 + 2048]);
    int cur = 0;
    for (int k0 = 0; k0 < DIM; k0 += 32) {
        __syncthreads();
        if (k0 + 32 < DIM) {
            const int nx = cur ^ 1;
            gload16(gA  + k0 + 32,                  &As[nx][wid*512]);
            gload16(gA  + k0 + 32 + (size_t)64*DIM, &As[nx][wid*512 + 2048]);
            gload16(gBv + k0 + 32,                  &Bv[nx][wid*512]);
            gload16(gBv + k0 + 32 + (size_t)64*DIM, &Bv[nx][wid*512 + 2048]);
            gload16(gBu + k0 + 32,                  &Bu[nx][wid*512]);
            gload16(gBu + k0 + 32 + (size_t)64*DIM, &Bu[nx][wid*512 + 2048]);
            gload16(gBz + k0 + 32,                  &Bz[nx][wid*512]);
            gload16(gBz + k0 + 32 + (size_t)64*DIM, &Bz[nx][wid*512 + 2048]);
        }
        bf16x8 af[4], bf_[4];
        #pragma unroll
        for (int mi = 0; mi < 4; ++mi)
            af[mi] = *(const bf16x8*)&As[cur][(wr*64 + mi*16 + fr)*32 + fq*8];
        #pragma unroll
        for (int ni = 0; ni < 4; ++ni)
            bf_[ni] = *(const bf16x8*)&Bv[cur][(wc*64 + ni*16 + fr)*32 + fq*8];
        #pragma unroll
        for (int mi = 0; mi < 4; ++mi)
            #pragma unroll
            for (int ni = 0; ni < 4; ++ni)
                accv[mi][ni] = __builtin_amdgcn_mfma_f32_16x16x32_bf16(af[mi], bf_[ni], accv[mi][ni], 0, 0, 0);
        #pragma unroll
        for (int ni = 0; ni < 4; ++ni)
            bf_[ni] = *(const bf16x8*)&Bu[cur][(wc*64 + ni*16 + fr)*32 + fq*8];
        #pragma unroll
        for (int mi = 0; mi < 4; ++mi)
            #pragma unroll
            for (int ni = 0; ni < 4; ++ni)
                accu[mi][ni] = __builtin_amdgcn_mfma_f32_16x16x32_bf16(af[mi], bf_[ni], accu[mi][ni], 0, 0, 0);
        #pragma unroll
        for (int ni = 0; ni < 4; ++ni)
            bf_[ni] = *(const bf16x8*)&Bz[cur][(wc*64 + ni*16 + fr)*32 + fq*8];
        #pragma unroll
        for (int mi = 0; mi < 4; ++mi)
            #pragma unroll
            for (int ni = 0; ni < 4; ++ni)
                accz[mi][ni] = __builtin_amdgcn_mfma_f32_16x16x32_bf16(af[mi], bf_[ni], accz[mi][ni], 0, 0, 0);
        cur ^= 1;
    }
    #pragma unroll
    for (int ni = 0; ni < 4; ++ni) {
        const int c = n0 + wc*64 + ni*16 + fr;
        const float bv = bias[c];
        const float bu = bias[512  + c];
        const float bz = bias[1024 + c];
        #pragma unroll
        for (int mi = 0; mi < 4; ++mi) {
            const int rbase = m0 + wr*64 + mi*16 + fq*4;
            #pragma unroll
            for (int j = 0; j < 4; ++j) {
                const size_t idx = (size_t)(rbase + j)*DIM + c;
                const float vv = accv[mi][ni][j] + bv;
                const float uu = accu[mi][ni][j] + bu;
                const float zz = accz[mi][ni][j] + bz;
                const float sg = 1.0f / (1.0f + __expf(-zz));
                Gb[idx] = f2bf(vv * sg);
                Ub[idx] = f2bf(uu);
            }
        }
    }
}

// ---------------------------------------------------------------- launcher
extern "C" void kernel_launch(void* const* d_in, const int* in_sizes, int n_in,
                              void* d_out, int out_size, void* d_ws, size_t ws_size,
                              hipStream_t stream) {
    const float* x      = (const float*)d_in[0];
    const float* w1     = (const float*)d_in[1];
    const float* b1     = (const float*)d_in[2];
    const float* w2     = (const float*)d_in[3];
    const float* b2     = (const float*)d_in[4];
    const float* w3     = (const float*)d_in[5];
    const float* b3     = (const float*)d_in[6];
    const float* conv_w = (const float*)d_in[7];
    const float* conv_b = (const float*)d_in[8];
    const float* w_in   = (const float*)d_in[9];
    const float* b_in   = (const float*)d_in[10];
    const float* w_out  = (const float*)d_in[11];
    const float* b_out  = (const float*)d_in[12];
    float* out = (float*)d_out;

    const size_t NEED = 167772160ULL;              // 160 MiB (known to fit)
    if (ws_size < NEED) return;
    char* ws = (char*)d_ws;
    float2*         Fbr    = (float2*)ws;                               // 32 MiB
    unsigned short* xb     = (unsigned short*)(ws + (size_t)( 32<<20)); // x bf16; later uT
    unsigned short* W2     = (unsigned short*)(ws + (size_t)( 64<<20)); // g0 / g
    unsigned short* W3     = (unsigned short*)(ws + (size_t)( 96<<20)); // filtT fp32 -> u (B,S,D)
    char*           W4     = ws + (size_t)(128<<20);
    float*          filt   = (float*)W4;
    float*          filtT  = (float*)(ws + (size_t)(96<<20));
    unsigned short* w_inT  = (unsigned short*)W4;                       // after filt dead
    unsigned short* w_outT = (unsigned short*)(W4 + (size_t)(2<<20));

    // 1. implicit filter MLP -> filt (S, D) fp32
    filter_mlp_kernel<<<NS, 64, 0, stream>>>(w1, b1, w2, b2, w3, b3, filt);
    // 2. transpose filt -> filtT (D, S) fp32
    transpose_f32_kernel<<<dim3(DIM/64, NS/64), 256, 0, stream>>>(filt, filtT, NS, DIM);
    // 3. filter spectrum (permuted order) -> Fbr
    fft_filt_kernel<<<DIM, FT, 0, stream>>>(filtT, Fbr);
    // 4. casts
    cast_x_kernel<<<(MTOT*DIM/8)/256, 256, 0, stream>>>(x, xb);
    castT_kernel<<<dim3(1536/64, DIM/64), 256, 0, stream>>>(w_in, w_inT, DIM, 1536);
    castT_kernel<<<dim3(DIM/64, DIM/64), 256, 0, stream>>>(w_out, w_outT, DIM, DIM);
    // 5. triple GEMM: g0 -> W2, u -> W3   (consumes filtT region: already dead)
    gemm_vzu_kernel<<<dim3(4, MTOT/128), 256, 0, stream>>>(xb, w_inT, b_in, W2, W3);
    // 6. depthwise conv + transpose: W3 (B,S,D) -> xb (B,D,S)   (xb dead as x)
    conv_transpose_kernel<<<NB*(NS/64)*(DIM/64), 256, 0, stream>>>(W3, conv_w, conv_b, xb);
    // 7. packed FFT circular conv, in-place on xb rows
    fft_conv_kernel<<<(NB/2)*DIM, FT, 0, stream>>>(xb, Fbr);
    // 8. g = g0 * y (transposed read of xb), in-place on W2
    gate_kernel<<<NB*(NS/64)*(DIM/64), 256, 0, stream>>>(W2, xb);
    // 9. out = g @ w_out + b_out -> d_out fp32
    gemm_bt_kernel<2><<<dim3(4, MTOT/128), 256, 0, stream>>>(W2, w_outT, b_out, out, nullptr);
}

// Round 9
// 258.977 us; speedup vs baseline: 1.1579x; 1.1579x over previous
//
#include <hip/hip_runtime.h>
#include <math.h>

#define DIM   512
#define NB    4
#define NS    8192
#define FFT_N 8192
#define FT    1024
#define MTOT  (NB*NS)

typedef __attribute__((ext_vector_type(8))) short bf16x8;
typedef __attribute__((ext_vector_type(4))) short short4v;
typedef __attribute__((ext_vector_type(8))) short short8v;
typedef __attribute__((ext_vector_type(4))) float f32x4;

// ---------------------------------------------------------------- helpers
__device__ __forceinline__ float bf2f(unsigned short u) {
    union { unsigned int i; float f; } v; v.i = ((unsigned int)u) << 16; return v.f;
}
__device__ __forceinline__ unsigned short f2bf(float f) {
    union { float f; unsigned int i; } v; v.f = f;
    unsigned int r = v.i + 0x7fffu + ((v.i >> 16) & 1u);
    return (unsigned short)(r >> 16);
}
__device__ __forceinline__ float2 cmulf(float2 a, float2 b) {
    return make_float2(a.x*b.x - a.y*b.y, a.x*b.y + a.y*b.x);
}
__device__ __forceinline__ float2 cadd(float2 a, float2 b) { return make_float2(a.x+b.x, a.y+b.y); }
__device__ __forceinline__ float2 csub(float2 a, float2 b) { return make_float2(a.x-b.x, a.y-b.y); }
__device__ __forceinline__ float gelu_exact(float x) {
    return 0.5f * x * (1.0f + erff(x * 0.70710678118654752f));
}
__device__ __forceinline__ void gload16(const void* g, void* l) {
    __builtin_amdgcn_global_load_lds((const __attribute__((address_space(1))) void*)g,
                                     (__attribute__((address_space(3))) void*)l, 16, 0, 0);
}

// ---------------------------------------------------------------- filter MLP
__global__ void filter_mlp_kernel(const float* __restrict__ w1, const float* __restrict__ b1,
                                  const float* __restrict__ w2, const float* __restrict__ b2,
                                  const float* __restrict__ w3, const float* __restrict__ b3,
                                  float* __restrict__ filt) {
    __shared__ float h1[64];
    __shared__ float h2[64];
    const int s = blockIdx.x;
    const int t = threadIdx.x;          // 64 threads
    const float pos = (float)s / (float)(NS - 1);
    h1[t] = gelu_exact(pos * w1[t] + b1[t]);
    __syncthreads();
    float acc = b2[t];
    #pragma unroll 8
    for (int j = 0; j < 64; ++j) acc += h1[j] * w2[j*64 + t];
    h2[t] = gelu_exact(acc);
    __syncthreads();
    for (int d = t; d < DIM; d += 64) {
        float o = b3[d];
        #pragma unroll 8
        for (int j = 0; j < 64; ++j) o += h2[j] * w3[j*DIM + d];
        filt[(size_t)s*DIM + d] = o;
    }
}

// ------------------------------------------------- fp32 transpose (R,C)->(C,R)
__global__ void transpose_f32_kernel(const float* __restrict__ in, float* __restrict__ out,
                                     int R, int C) {
    __shared__ float tile[64][65];
    const int c0 = blockIdx.x * 64, r0 = blockIdx.y * 64;
    const int t = threadIdx.x;
    const int rr = t >> 4, c4 = (t & 15) * 4;
    #pragma unroll
    for (int p = 0; p < 4; ++p) {
        const int r = rr + p*16;
        float4 v = *(const float4*)&in[(size_t)(r0 + r)*C + c0 + c4];
        tile[r][c4+0]=v.x; tile[r][c4+1]=v.y; tile[r][c4+2]=v.z; tile[r][c4+3]=v.w;
    }
    __syncthreads();
    const int cc = t >> 4, r4 = (t & 15) * 4;
    #pragma unroll
    for (int p = 0; p < 4; ++p) {
        const int c = cc + p*16;
        float4 o = make_float4(tile[r4+0][c], tile[r4+1][c], tile[r4+2][c], tile[r4+3][c]);
        *(float4*)&out[(size_t)(c0 + c)*R + r0 + r4] = o;
    }
}

// ------------------------------------------- cast+transpose (R,C)f32->(C,R)bf16
__global__ void castT_kernel(const float* __restrict__ in, unsigned short* __restrict__ outT,
                             int R, int C) {
    __shared__ float tile[64][65];
    const int c0 = blockIdx.x * 64, r0 = blockIdx.y * 64;
    const int t = threadIdx.x;
    const int rr = t >> 4, c4 = (t & 15) * 4;
    #pragma unroll
    for (int p = 0; p < 4; ++p) {
        const int r = rr + p*16;
        float4 v = *(const float4*)&in[(size_t)(r0 + r)*C + c0 + c4];
        tile[r][c4+0]=v.x; tile[r][c4+1]=v.y; tile[r][c4+2]=v.z; tile[r][c4+3]=v.w;
    }
    __syncthreads();
    const int cc = t >> 4, r4 = (t & 15) * 4;
    #pragma unroll
    for (int p = 0; p < 4; ++p) {
        const int c = cc + p*16;
        short4v o;
        o[0] = (short)f2bf(tile[r4+0][c]); o[1] = (short)f2bf(tile[r4+1][c]);
        o[2] = (short)f2bf(tile[r4+2][c]); o[3] = (short)f2bf(tile[r4+3][c]);
        *(short4v*)&outT[(size_t)(c0 + c)*R + r0 + r4] = o;
    }
}

// ---------------------------------------------------------------- cast x->bf16
__global__ void cast_x_kernel(const float* __restrict__ in, unsigned short* __restrict__ out) {
    const size_t i = ((size_t)blockIdx.x * 256 + threadIdx.x) * 8;
    float4 a = *(const float4*)&in[i];
    float4 b = *(const float4*)&in[i+4];
    short8v o;
    o[0]=(short)f2bf(a.x); o[1]=(short)f2bf(a.y); o[2]=(short)f2bf(a.z); o[3]=(short)f2bf(a.w);
    o[4]=(short)f2bf(b.x); o[5]=(short)f2bf(b.y); o[6]=(short)f2bf(b.z); o[7]=(short)f2bf(b.w);
    *(short8v*)&out[i] = o;
}

// ---------------------------------------------------------------- FFT pieces
template<int LOGQ>
__device__ __forceinline__ void dif4_stage(float2* X) {
    const int q = 1 << LOGQ;
    const float step = -6.28318530717958647692f / (float)(4*q);
    #pragma unroll
    for (int it = 0; it < (FFT_N/4)/FT; ++it) {
        const int idx = threadIdx.x + it*FT;
        const int g = idx >> LOGQ, k = idx & (q-1);
        const int base = (g << (LOGQ+2)) + k;
        float2 a=X[base], b=X[base+q], c=X[base+2*q], d=X[base+3*q];
        float2 t0=cadd(a,c), t1=csub(a,c), t2=cadd(b,d), t3=csub(b,d);
        float2 y0=cadd(t0,t2), y2=csub(t0,t2);
        float2 y1=make_float2(t1.x+t3.y, t1.y-t3.x);   // t1 - i*t3
        float2 y3=make_float2(t1.x-t3.y, t1.y+t3.x);   // t1 + i*t3
        float sv, cv; __sincosf(step*(float)k, &sv, &cv);
        float2 w1=make_float2(cv, sv);
        float2 w2=cmulf(w1, w1);
        float2 w3=cmulf(w2, w1);
        X[base]     = y0;
        X[base+q]   = cmulf(y1, w1);
        X[base+2*q] = cmulf(y2, w2);
        X[base+3*q] = cmulf(y3, w3);
    }
    __syncthreads();
}

template<int LOGQ>
__device__ __forceinline__ void dit4_stage_inv(float2* X) {
    const int q = 1 << LOGQ;
    const float step = 6.28318530717958647692f / (float)(4*q);
    #pragma unroll
    for (int it = 0; it < (FFT_N/4)/FT; ++it) {
        const int idx = threadIdx.x + it*FT;
        const int g = idx >> LOGQ, k = idx & (q-1);
        const int base = (g << (LOGQ+2)) + k;
        float sv, cv; __sincosf(step*(float)k, &sv, &cv);
        float2 w1=make_float2(cv, sv);
        float2 w2=cmulf(w1, w1);
        float2 w3=cmulf(w2, w1);
        float2 u0=X[base];
        float2 u1=cmulf(X[base+q],   w1);
        float2 u2=cmulf(X[base+2*q], w2);
        float2 u3=cmulf(X[base+3*q], w3);
        float2 s02=cadd(u0,u2), d02=csub(u0,u2);
        float2 s13=cadd(u1,u3), d13=csub(u1,u3);
        X[base]     = cadd(s02, s13);
        X[base+2*q] = csub(s02, s13);
        X[base+q]   = make_float2(d02.x - d13.y, d02.y + d13.x);   // d02 + i*d13
        X[base+3*q] = make_float2(d02.x + d13.y, d02.y - d13.x);   // d02 - i*d13
    }
    __syncthreads();
}

__device__ __forceinline__ void reg_fwd(float2* E) {
    const float C = 0.70710678118654752f;
    {
        float2 t0=cadd(E[0],E[4]), t1=csub(E[0],E[4]);
        float2 t2=cadd(E[2],E[6]), t3=csub(E[2],E[6]);
        E[0]=cadd(t0,t2);
        E[4]=csub(t0,t2);
        E[2]=make_float2(t1.x+t3.y, t1.y-t3.x);
        E[6]=make_float2(t1.x-t3.y, t1.y+t3.x);
    }
    {
        float2 t0=cadd(E[1],E[5]), t1=csub(E[1],E[5]);
        float2 t2=cadd(E[3],E[7]), t3=csub(E[3],E[7]);
        float2 y0=cadd(t0,t2), y2=csub(t0,t2);
        float2 y1=make_float2(t1.x+t3.y, t1.y-t3.x);
        float2 y3=make_float2(t1.x-t3.y, t1.y+t3.x);
        E[1]=y0;
        E[3]=make_float2(C*(y1.x+y1.y),  C*(y1.y-y1.x));
        E[5]=make_float2(y2.y, -y2.x);
        E[7]=make_float2(C*(y3.y-y3.x), -C*(y3.x+y3.y));
    }
    #pragma unroll
    for (int j = 0; j < 8; j += 2) {
        float2 a=E[j], b=E[j+1];
        E[j]=cadd(a,b); E[j+1]=csub(a,b);
    }
}
__device__ __forceinline__ void reg_inv(float2* E) {
    const float C = 0.70710678118654752f;
    #pragma unroll
    for (int j = 0; j < 8; j += 2) {
        float2 a=E[j], b=E[j+1];
        E[j]=cadd(a,b); E[j+1]=csub(a,b);
    }
    {
        float2 u0=E[0], u1=E[2], u2=E[4], u3=E[6];
        float2 s02=cadd(u0,u2), d02=csub(u0,u2);
        float2 s13=cadd(u1,u3), d13=csub(u1,u3);
        E[0]=cadd(s02,s13);
        E[4]=csub(s02,s13);
        E[2]=make_float2(d02.x - d13.y, d02.y + d13.x);
        E[6]=make_float2(d02.x + d13.y, d02.y - d13.x);
    }
    {
        float2 z1=E[3], z2=E[5], z3=E[7];
        float2 u0=E[1];
        float2 u1=make_float2(C*(z1.x - z1.y), C*(z1.x + z1.y));
        float2 u2=make_float2(-z2.y, z2.x);
        float2 u3=make_float2(-C*(z3.x + z3.y), C*(z3.x - z3.y));
        float2 s02=cadd(u0,u2), d02=csub(u0,u2);
        float2 s13=cadd(u1,u3), d13=csub(u1,u3);
        E[1]=cadd(s02,s13);
        E[5]=csub(s02,s13);
        E[3]=make_float2(d02.x - d13.y, d02.y + d13.x);
        E[7]=make_float2(d02.x + d13.y, d02.y - d13.x);
    }
}

__device__ __forceinline__ void load8(const float2* X, int t, float2* E) {
    const float4* b = (const float4*)(X + 8*t);
    #pragma unroll
    for (int p = 0; p < 4; ++p) {
        float4 v = b[p];
        E[2*p]   = make_float2(v.x, v.y);
        E[2*p+1] = make_float2(v.z, v.w);
    }
}
__device__ __forceinline__ void store8(float2* X, int t, const float2* E) {
    float4* b = (float4*)(X + 8*t);
    #pragma unroll
    for (int p = 0; p < 4; ++p)
        b[p] = make_float4(E[2*p].x, E[2*p].y, E[2*p+1].x, E[2*p+1].y);
}

// filter spectrum (permuted order P); filtT (D, S) fp32 rows
__global__ __launch_bounds__(FT)
void fft_filt_kernel(const float* __restrict__ filtT, float2* __restrict__ Fbr) {
    extern __shared__ float4 Xraw[];
    float2* X = (float2*)Xraw;
    const int dd = blockIdx.x;
    const int t = threadIdx.x;
    const float* f = filtT + (size_t)dd * FFT_N;
    {
        float4 a = *(const float4*)(f + 8*t);
        float4 b = *(const float4*)(f + 8*t + 4);
        float2 E[8];
        E[0]=make_float2(a.x,0.f); E[1]=make_float2(a.y,0.f);
        E[2]=make_float2(a.z,0.f); E[3]=make_float2(a.w,0.f);
        E[4]=make_float2(b.x,0.f); E[5]=make_float2(b.y,0.f);
        E[6]=make_float2(b.z,0.f); E[7]=make_float2(b.w,0.f);
        store8(X, t, E);
    }
    __syncthreads();
    dif4_stage<11>(X);
    dif4_stage<9>(X);
    dif4_stage<7>(X);
    dif4_stage<5>(X);
    dif4_stage<3>(X);
    {
        float2 E[8];
        load8(X, t, E);
        reg_fwd(E);
        float2* o = Fbr + (size_t)dd*FFT_N + 8*t;
        #pragma unroll
        for (int j = 0; j < 8; ++j) o[j] = E[j];
    }
}

// packed-pair circular conv, in-place bf16: rows (2p,d) and (2p+1,d) of uT
__global__ __launch_bounds__(FT)
void fft_conv_kernel(unsigned short* __restrict__ uT, const float2* __restrict__ Fbr) {
    extern __shared__ float4 Xraw[];
    float2* X = (float2*)Xraw;
    const int d = blockIdx.x & (DIM - 1);
    const int p = blockIdx.x >> 9;
    unsigned short* u1 = uT + (size_t)((2*p    )*DIM + d) * FFT_N;
    unsigned short* u2 = uT + (size_t)((2*p + 1)*DIM + d) * FFT_N;
    const int t = threadIdx.x;
    {
        short8v a = *(const short8v*)(u1 + 8*t);
        short8v b = *(const short8v*)(u2 + 8*t);
        float2 E[8];
        #pragma unroll
        for (int j = 0; j < 8; ++j)
            E[j] = make_float2(bf2f((unsigned short)a[j]), bf2f((unsigned short)b[j]));
        store8(X, t, E);
    }
    __syncthreads();
    dif4_stage<11>(X);
    dif4_stage<9>(X);
    dif4_stage<7>(X);
    dif4_stage<5>(X);
    dif4_stage<3>(X);
    {
        float2 E[8];
        load8(X, t, E);
        reg_fwd(E);
        const float2* F = Fbr + (size_t)d*FFT_N + 8*t;
        #pragma unroll
        for (int j = 0; j < 8; ++j) E[j] = cmulf(E[j], F[j]);
        reg_inv(E);
        store8(X, t, E);
    }
    __syncthreads();
    dit4_stage_inv<3>(X);
    dit4_stage_inv<5>(X);
    dit4_stage_inv<7>(X);
    dit4_stage_inv<9>(X);
    dit4_stage_inv<11>(X);
    {
        float2 E[8];
        load8(X, t, E);
        const float sc = 1.0f / (float)FFT_N;
        short8v a, b;
        #pragma unroll
        for (int j = 0; j < 8; ++j) {
            a[j] = (short)f2bf(E[j].x * sc);
            b[j] = (short)f2bf(E[j].y * sc);
        }
        *(short8v*)(u1 + 8*t) = a;
        *(short8v*)(u2 + 8*t) = b;
    }
}

// ------------------------------------------------- depthwise conv + transpose
__global__ void conv_transpose_kernel(const unsigned short* __restrict__ u,
                                      const float* __restrict__ conv_w,
                                      const float* __restrict__ conv_b,
                                      unsigned short* __restrict__ uT) {
    __shared__ float tile[66][65];
    const int bid = blockIdx.x;
    const int dt = bid & 7, st = (bid >> 3) & 127, b = bid >> 10;
    const int d0 = dt*64, s0 = st*64;
    const int t = threadIdx.x;
    const int rr = t >> 4, c4 = (t & 15) * 4;
    for (int r = rr; r < 66; r += 16) {
        const int s = s0 + r - 1;
        float v0=0.f, v1=0.f, v2=0.f, v3=0.f;
        if (s >= 0 && s < NS) {
            short4v xv = *(const short4v*)&u[((size_t)(b*NS + s))*DIM + d0 + c4];
            v0=bf2f((unsigned short)xv[0]); v1=bf2f((unsigned short)xv[1]);
            v2=bf2f((unsigned short)xv[2]); v3=bf2f((unsigned short)xv[3]);
        }
        tile[r][c4]=v0; tile[r][c4+1]=v1; tile[r][c4+2]=v2; tile[r][c4+3]=v3;
    }
    __syncthreads();
    const int dl = t >> 4, s4 = (t & 15) * 4;
    #pragma unroll
    for (int p = 0; p < 4; ++p) {
        const int dc = dl + p*16;
        const int d = d0 + dc;
        const float w0 = conv_w[d*3], w1 = conv_w[d*3+1], w2 = conv_w[d*3+2];
        const float cb = conv_b[d];
        short4v o;
        #pragma unroll
        for (int j = 0; j < 4; ++j) {
            const int sx = s4 + j;
            const float val = tile[sx][dc]*w0 + tile[sx+1][dc]*w1 + tile[sx+2][dc]*w2 + cb;
            o[j] = (short)f2bf(val);
        }
        *(short4v*)&uT[((size_t)(b*DIM + d))*FFT_N + s0 + s4] = o;
    }
}

// ---------------------------------------------------------------- gating
// vg (B,S,D) bf16 *= y from yT (B,D,S) bf16 (in-place)
__global__ void gate_kernel(unsigned short* __restrict__ vg, const unsigned short* __restrict__ yT) {
    __shared__ float tile[64][65];
    const int bid = blockIdx.x;
    const int dt = bid & 7, st = (bid >> 3) & 127, b = bid >> 10;
    const int d0 = dt*64, s0 = st*64;
    const int t = threadIdx.x;
    const int dl = t >> 4, s4 = (t & 15) * 4;
    #pragma unroll
    for (int p = 0; p < 4; ++p) {
        const int d = dl + p*16;
        short4v y = *(const short4v*)&yT[((size_t)(b*DIM + d0 + d))*FFT_N + s0 + s4];
        tile[d][s4]  =bf2f((unsigned short)y[0]); tile[d][s4+1]=bf2f((unsigned short)y[1]);
        tile[d][s4+2]=bf2f((unsigned short)y[2]); tile[d][s4+3]=bf2f((unsigned short)y[3]);
    }
    __syncthreads();
    const int sl = t >> 4, d4 = (t & 15) * 4;
    #pragma unroll
    for (int p = 0; p < 4; ++p) {
        const int s = s0 + sl + p*16;
        unsigned short* pv = &vg[((size_t)(b*NS + s))*DIM + d0 + d4];
        short4v v = *(short4v*)pv;
        short4v o;
        #pragma unroll
        for (int j = 0; j < 4; ++j)
            o[j] = (short)f2bf(bf2f((unsigned short)v[j]) * tile[d4+j][sl + p*16]);
        *(short4v*)pv = o;
    }
}

// ---------------------------------------------------------------- bf16 GEMM
// Double-buffered pipeline + XCD swizzle. Grid must be dim3(4, 256).
// MODE 0: Cb = bf16(val);  MODE 2: Cf = val (fp32)
template<int MODE>
__global__ __launch_bounds__(256)
void gemm_bt_kernel(const unsigned short* __restrict__ A,
                    const unsigned short* __restrict__ BT,
                    const float* __restrict__ bias,
                    float* __restrict__ Cf,
                    unsigned short* __restrict__ Cb) {
    __shared__ unsigned short As[2][4096];
    __shared__ unsigned short Bs[2][4096];
    const int tid = threadIdx.x;
    const int wid = tid >> 6, lane = tid & 63;
    const int bid = blockIdx.y * 4 + blockIdx.x;
    const int swz = (bid & 7) * 128 + (bid >> 3);
    const int m0 = (swz >> 2) * 128, n0 = (swz & 3) * 128;
    const int srow = wid*16 + (lane >> 2);
    const int scol = (lane & 3) * 8;
    const unsigned short* gA = A  + (size_t)(m0 + srow)*DIM + scol;
    const unsigned short* gB = BT + (size_t)(n0 + srow)*DIM + scol;
    const int wr = wid >> 1, wc = wid & 1;
    const int fr = lane & 15, fq = lane >> 4;
    f32x4 acc[4][4] = {};
    gload16(gA,                  &As[0][wid*512]);
    gload16(gA + (size_t)64*DIM, &As[0][wid*512 + 2048]);
    gload16(gB,                  &Bs[0][wid*512]);
    gload16(gB + (size_t)64*DIM, &Bs[0][wid*512 + 2048]);
    int cur = 0;
    for (int k0 = 0; k0 < DIM; k0 += 32) {
        __syncthreads();
        if (k0 + 32 < DIM) {
            const int nx = cur ^ 1;
            gload16(gA + k0 + 32,                  &As[nx][wid*512]);
            gload16(gA + k0 + 32 + (size_t)64*DIM, &As[nx][wid*512 + 2048]);
            gload16(gB + k0 + 32,                  &Bs[nx][wid*512]);
            gload16(gB + k0 + 32 + (size_t)64*DIM, &Bs[nx][wid*512 + 2048]);
        }
        bf16x8 af[4], bfr[4];
        #pragma unroll
        for (int mi = 0; mi < 4; ++mi)
            af[mi] = *(const bf16x8*)&As[cur][(wr*64 + mi*16 + fr)*32 + fq*8];
        #pragma unroll
        for (int ni = 0; ni < 4; ++ni)
            bfr[ni] = *(const bf16x8*)&Bs[cur][(wc*64 + ni*16 + fr)*32 + fq*8];
        #pragma unroll
        for (int mi = 0; mi < 4; ++mi)
            #pragma unroll
            for (int ni = 0; ni < 4; ++ni)
                acc[mi][ni] = __builtin_amdgcn_mfma_f32_16x16x32_bf16(af[mi], bfr[ni], acc[mi][ni], 0, 0, 0);
        cur ^= 1;
    }
    #pragma unroll
    for (int ni = 0; ni < 4; ++ni) {
        const int c = n0 + wc*64 + ni*16 + fr;
        const float bv = bias[c];
        #pragma unroll
        for (int mi = 0; mi < 4; ++mi) {
            const int rbase = m0 + wr*64 + mi*16 + fq*4;
            #pragma unroll
            for (int j = 0; j < 4; ++j) {
                const size_t idx = (size_t)(rbase + j)*DIM + c;
                const float val = acc[mi][ni][j] + bv;
                if (MODE == 0) Cb[idx] = f2bf(val);
                else           Cf[idx] = val;
            }
        }
    }
}

// ------- merged dispatch: blocks 0..1023 -> g0 = (v+bv)*sigmoid(z+bz) (2 accs)
//                          blocks 1024..2047 -> u = x@Wu+bu           (1 acc)
// grid must be dim3(4, 512). LDS stays 48KB (R6 profile), block-uniform branch.
__global__ __launch_bounds__(256)
void gemm_vzu2_kernel(const unsigned short* __restrict__ A,
                      const unsigned short* __restrict__ BT,   // w_inT (1536,512)
                      const float* __restrict__ bias,          // b_in (1536)
                      unsigned short* __restrict__ Gb,         // g0 (B,S,D)
                      unsigned short* __restrict__ Ub) {       // u  (B,S,D)
    __shared__ unsigned short As[2][4096];
    __shared__ unsigned short B1[2][4096];
    __shared__ unsigned short B2[2][4096];
    const int tid = threadIdx.x;
    const int wid = tid >> 6, lane = tid & 63;
    const int bid = blockIdx.y * 4 + blockIdx.x;
    const bool is_u = bid >= 1024;
    const int lbid = bid & 1023;
    const int swz = (lbid & 7) * 128 + (lbid >> 3);
    const int m0 = (swz >> 2) * 128, n0 = (swz & 3) * 128;
    const int srow = wid*16 + (lane >> 2);
    const int scol = (lane & 3) * 8;
    const unsigned short* gA = A + (size_t)(m0 + srow)*DIM + scol;
    const int wr = wid >> 1, wc = wid & 1;
    const int fr = lane & 15, fq = lane >> 4;

    if (!is_u) {
        const unsigned short* gBv = BT + (size_t)(n0 + srow)*DIM + scol;
        const unsigned short* gBz = BT + (size_t)(1024 + n0 + srow)*DIM + scol;
        f32x4 accv[4][4] = {};
        f32x4 accz[4][4] = {};
        gload16(gA,                   &As[0][wid*512]);
        gload16(gA  + (size_t)64*DIM, &As[0][wid*512 + 2048]);
        gload16(gBv,                  &B1[0][wid*512]);
        gload16(gBv + (size_t)64*DIM, &B1[0][wid*512 + 2048]);
        gload16(gBz,                  &B2[0][wid*512]);
        gload16(gBz + (size_t)64*DIM, &B2[0][wid*512 + 2048]);
        int cur = 0;
        for (int k0 = 0; k0 < DIM; k0 += 32) {
            __syncthreads();
            if (k0 + 32 < DIM) {
                const int nx = cur ^ 1;
                gload16(gA  + k0 + 32,                  &As[nx][wid*512]);
                gload16(gA  + k0 + 32 + (size_t)64*DIM, &As[nx][wid*512 + 2048]);
                gload16(gBv + k0 + 32,                  &B1[nx][wid*512]);
                gload16(gBv + k0 + 32 + (size_t)64*DIM, &B1[nx][wid*512 + 2048]);
                gload16(gBz + k0 + 32,                  &B2[nx][wid*512]);
                gload16(gBz + k0 + 32 + (size_t)64*DIM, &B2[nx][wid*512 + 2048]);
            }
            bf16x8 af[4], bf_[4];
            #pragma unroll
            for (int mi = 0; mi < 4; ++mi)
                af[mi] = *(const bf16x8*)&As[cur][(wr*64 + mi*16 + fr)*32 + fq*8];
            #pragma unroll
            for (int ni = 0; ni < 4; ++ni)
                bf_[ni] = *(const bf16x8*)&B1[cur][(wc*64 + ni*16 + fr)*32 + fq*8];
            #pragma unroll
            for (int mi = 0; mi < 4; ++mi)
                #pragma unroll
                for (int ni = 0; ni < 4; ++ni)
                    accv[mi][ni] = __builtin_amdgcn_mfma_f32_16x16x32_bf16(af[mi], bf_[ni], accv[mi][ni], 0, 0, 0);
            #pragma unroll
            for (int ni = 0; ni < 4; ++ni)
                bf_[ni] = *(const bf16x8*)&B2[cur][(wc*64 + ni*16 + fr)*32 + fq*8];
            #pragma unroll
            for (int mi = 0; mi < 4; ++mi)
                #pragma unroll
                for (int ni = 0; ni < 4; ++ni)
                    accz[mi][ni] = __builtin_amdgcn_mfma_f32_16x16x32_bf16(af[mi], bf_[ni], accz[mi][ni], 0, 0, 0);
            cur ^= 1;
        }
        #pragma unroll
        for (int ni = 0; ni < 4; ++ni) {
            const int c = n0 + wc*64 + ni*16 + fr;
            const float bv = bias[c];
            const float bz = bias[1024 + c];
            #pragma unroll
            for (int mi = 0; mi < 4; ++mi) {
                const int rbase = m0 + wr*64 + mi*16 + fq*4;
                #pragma unroll
                for (int j = 0; j < 4; ++j) {
                    const size_t idx = (size_t)(rbase + j)*DIM + c;
                    const float vv = accv[mi][ni][j] + bv;
                    const float zz = accz[mi][ni][j] + bz;
                    const float sg = 1.0f / (1.0f + __expf(-zz));
                    Gb[idx] = f2bf(vv * sg);
                }
            }
        }
    } else {
        const unsigned short* gBu = BT + (size_t)(512 + n0 + srow)*DIM + scol;
        f32x4 acc[4][4] = {};
        gload16(gA,                   &As[0][wid*512]);
        gload16(gA  + (size_t)64*DIM, &As[0][wid*512 + 2048]);
        gload16(gBu,                  &B1[0][wid*512]);
        gload16(gBu + (size_t)64*DIM, &B1[0][wid*512 + 2048]);
        int cur = 0;
        for (int k0 = 0; k0 < DIM; k0 += 32) {
            __syncthreads();
            if (k0 + 32 < DIM) {
                const int nx = cur ^ 1;
                gload16(gA  + k0 + 32,                  &As[nx][wid*512]);
                gload16(gA  + k0 + 32 + (size_t)64*DIM, &As[nx][wid*512 + 2048]);
                gload16(gBu + k0 + 32,                  &B1[nx][wid*512]);
                gload16(gBu + k0 + 32 + (size_t)64*DIM, &B1[nx][wid*512 + 2048]);
            }
            bf16x8 af[4], bf_[4];
            #pragma unroll
            for (int mi = 0; mi < 4; ++mi)
                af[mi] = *(const bf16x8*)&As[cur][(wr*64 + mi*16 + fr)*32 + fq*8];
            #pragma unroll
            for (int ni = 0; ni < 4; ++ni)
                bf_[ni] = *(const bf16x8*)&B1[cur][(wc*64 + ni*16 + fr)*32 + fq*8];
            #pragma unroll
            for (int mi = 0; mi < 4; ++mi)
                #pragma unroll
                for (int ni = 0; ni < 4; ++ni)
                    acc[mi][ni] = __builtin_amdgcn_mfma_f32_16x16x32_bf16(af[mi], bf_[ni], acc[mi][ni], 0, 0, 0);
            cur ^= 1;
        }
        #pragma unroll
        for (int ni = 0; ni < 4; ++ni) {
            const int c = n0 + wc*64 + ni*16 + fr;
            const float bu = bias[512 + c];
            #pragma unroll
            for (int mi = 0; mi < 4; ++mi) {
                const int rbase = m0 + wr*64 + mi*16 + fq*4;
                #pragma unroll
                for (int j = 0; j < 4; ++j) {
                    const size_t idx = (size_t)(rbase + j)*DIM + c;
                    Ub[idx] = f2bf(acc[mi][ni][j] + bu);
                }
            }
        }
    }
}

// ---------------------------------------------------------------- launcher
extern "C" void kernel_launch(void* const* d_in, const int* in_sizes, int n_in,
                              void* d_out, int out_size, void* d_ws, size_t ws_size,
                              hipStream_t stream) {
    const float* x      = (const float*)d_in[0];
    const float* w1     = (const float*)d_in[1];
    const float* b1     = (const float*)d_in[2];
    const float* w2     = (const float*)d_in[3];
    const float* b2     = (const float*)d_in[4];
    const float* w3     = (const float*)d_in[5];
    const float* b3     = (const float*)d_in[6];
    const float* conv_w = (const float*)d_in[7];
    const float* conv_b = (const float*)d_in[8];
    const float* w_in   = (const float*)d_in[9];
    const float* b_in   = (const float*)d_in[10];
    const float* w_out  = (const float*)d_in[11];
    const float* b_out  = (const float*)d_in[12];
    float* out = (float*)d_out;

    const size_t NEED = 167772160ULL;              // 160 MiB (known to fit)
    if (ws_size < NEED) return;
    char* ws = (char*)d_ws;
    float2*         Fbr    = (float2*)ws;                               // 32 MiB
    unsigned short* xb     = (unsigned short*)(ws + (size_t)( 32<<20)); // x bf16; later uT
    unsigned short* W2     = (unsigned short*)(ws + (size_t)( 64<<20)); // g0 / g
    unsigned short* W3     = (unsigned short*)(ws + (size_t)( 96<<20)); // filtT fp32 -> u (B,S,D)
    char*           W4     = ws + (size_t)(128<<20);
    float*          filt   = (float*)W4;
    float*          filtT  = (float*)(ws + (size_t)(96<<20));
    unsigned short* w_inT  = (unsigned short*)W4;                       // after filt dead
    unsigned short* w_outT = (unsigned short*)(W4 + (size_t)(2<<20));

    // 1. implicit filter MLP -> filt (S, D) fp32
    filter_mlp_kernel<<<NS, 64, 0, stream>>>(w1, b1, w2, b2, w3, b3, filt);
    // 2. transpose filt -> filtT (D, S) fp32
    transpose_f32_kernel<<<dim3(DIM/64, NS/64), 256, 0, stream>>>(filt, filtT, NS, DIM);
    // 3. filter spectrum (permuted order) -> Fbr
    fft_filt_kernel<<<DIM, FT, FFT_N*sizeof(float2), stream>>>(filtT, Fbr);
    // 4. casts
    cast_x_kernel<<<(MTOT*DIM/8)/256, 256, 0, stream>>>(x, xb);
    castT_kernel<<<dim3(1536/64, DIM/64), 256, 0, stream>>>(w_in, w_inT, DIM, 1536);
    castT_kernel<<<dim3(DIM/64, DIM/64), 256, 0, stream>>>(w_out, w_outT, DIM, DIM);
    // 5. merged dispatch: g0 -> W2 (1024 blocks) and u -> W3 (1024 blocks)
    gemm_vzu2_kernel<<<dim3(4, 512), 256, 0, stream>>>(xb, w_inT, b_in, W2, W3);
    // 6. depthwise conv + transpose: W3 (B,S,D) -> xb (B,D,S)   (xb dead as x)
    conv_transpose_kernel<<<NB*(NS/64)*(DIM/64), 256, 0, stream>>>(W3, conv_w, conv_b, xb);
    // 7. packed FFT circular conv, in-place on xb rows
    fft_conv_kernel<<<(NB/2)*DIM, FT, FFT_N*sizeof(float2), stream>>>(xb, Fbr);
    // 8. g = g0 * y (transposed read of xb), in-place on W2
    gate_kernel<<<NB*(NS/64)*(DIM/64), 256, 0, stream>>>(W2, xb);
    // 9. out = g @ w_out + b_out -> d_out fp32
    gemm_bt_kernel<2><<<dim3(4, MTOT/128), 256, 0, stream>>>(W2, w_outT, b_out, out, nullptr);
}